// Round 18
// baseline (144.558 us; speedup 1.0000x reference)
//
#include <hip/hip_runtime.h>

typedef __bf16 bf16x8 __attribute__((ext_vector_type(8)));
typedef float f32x4 __attribute__((ext_vector_type(4)));

#define TWO_LOG2E 2.88539008177792681f   // 2*log2(e): exp(2x) = exp2(x*TWO_LOG2E)

#define GLOADLDS16(g, l) __builtin_amdgcn_global_load_lds(                     \
    (const __attribute__((address_space(1))) void*)(g),                        \
    (__attribute__((address_space(3))) void*)(l), 16, 0, 0)

__device__ __forceinline__ unsigned f2bf(float f) {
    unsigned u = __float_as_uint(f);
    return (u + 0x7FFFu + ((u >> 16) & 1u)) >> 16;   // RNE
}

// ---------------- kernel 1: row-normalize z=[z1;z2] -> bf16 zn[8192][256] ---------------
// Blocks 0..31 also zero S[8192]; block 32 zeroes out[0]. (Proven form.)
__global__ void __launch_bounds__(256) normalize_kernel(
    const float* __restrict__ z1, const float* __restrict__ z2,
    unsigned short* __restrict__ zn, float* __restrict__ S, float* __restrict__ out)
{
    if (blockIdx.x < 32) S[(blockIdx.x << 8) + threadIdx.x] = 0.f;
    if (blockIdx.x == 32 && threadIdx.x == 0) out[0] = 0.f;

    const int wave = threadIdx.x >> 6, lane = threadIdx.x & 63;
    const int row = (blockIdx.x << 2) + wave;               // 2048 blocks * 4 rows
    const float* src = (row < 4096) ? (z1 + row * 256) : (z2 + (row - 4096) * 256);
    float4 v = ((const float4*)src)[lane];                  // 64 lanes * 4 = 256
    float ss = v.x * v.x + v.y * v.y + v.z * v.z + v.w * v.w;
#pragma unroll
    for (int m = 32; m > 0; m >>= 1) ss += __shfl_xor(ss, m, 64);
    float sc = 1.0f / fmaxf(sqrtf(ss), 1e-8f);
    uint2 w;
    w.x = f2bf(v.x * sc) | (f2bf(v.y * sc) << 16);
    w.y = f2bf(v.z * sc) | (f2bf(v.w * sc) << 16);
    *(uint2*)(zn + row * 256 + (lane << 2)) = w;
}

// ---------------- kernel 2: TRIANGULAR wave-autonomous sim-exp (R15 pipeline) -----------
// sim is symmetric: only tiles with colRun >= strip's diagonal run are computed; each
// job adds row sums (j>=i) AND transposed col sums (j>i). 2112 equal jobs = (strip si
// of 64 rows) x (run rn of 256 cols), rn >= si/4. Per job: R15's proven 2KB-chunk ring
// pipeline (ring of FOUR 2KB wave-private LDS buffers, global_load_lds, steady-state
// `s_waitcnt vmcnt(6)` = 3 stages in flight — the waits order DMA->ds_read, which the
// compiler does NOT model (R9 NaN); tail drains 6->4->2->0). Row sums in rs[4][4],
// col sums in cs[16] registers; ONE flush (16 row + 256 col atomics) at job end.
// Only the diagonal-straddling run (rn == si/4) applies per-element predicates.
// Diagonal counted row-side; kernel 3 subtracts e^{sim_ii}. No __syncthreads.
__global__ void __launch_bounds__(64, 2) simexp_kernel(
    const unsigned short* __restrict__ zn, float* __restrict__ S)
{
    __shared__ __align__(16) unsigned short Bs[4][1024];    // 4 x 2 KB ring, wave-private

    const int lane = threadIdx.x;
    const int q = lane >> 4, n16 = lane & 15;

    // decode job -> (si, rn): strip-group v = si>>2 has 4 strips x (32-v) runs
    int t = blockIdx.x, v = 0;
    while (t >= ((32 - v) << 2)) { t -= (32 - v) << 2; ++v; }
    const int si = (v << 2) + t / (32 - v);
    const int rn = v + t % (32 - v);
    const int rowBase = si << 6;                // 64 rows
    const int colRun  = rn << 8;                // 256 cols
    const bool strad = (rn == v);               // run containing the diagonal block

    // A: 64 rows x K=256 in registers
    bf16x8 a[4][8];
#pragma unroll
    for (int rt = 0; rt < 4; ++rt)
#pragma unroll
        for (int ks = 0; ks < 8; ++ks)
            a[rt][ks] = *(const bf16x8*)(zn + ((rowBase + (rt << 4) + n16) << 8)
                                            + (ks << 5) + (q << 3));

    // stage chunk m (col-chunk m>>3 of 32 cols, k-chunk m&7 of 32): 2KB, 2 loads
    auto stage = [&](int m) {
        const int colBase = colRun + ((m >> 3) << 5);
        const int koff = (m & 7) << 5;          // elems
        unsigned short* base = (unsigned short*)&Bs[0][0] + ((m & 3) << 10);
#pragma unroll
        for (int p = 0; p < 2; ++p) {
            int s = (p << 6) + lane;            // 16B slot 0..127
            int c = s >> 2, d = s & 3;
            int k8 = d ^ (c & 3);               // XOR swizzle
            GLOADLDS16(zn + ((colBase + c) << 8) + koff + (k8 << 3), base + (s << 3));
        }
    };

    float rs[4][4];                             // row sums
    float cs[16];                               // col sums: idx = cc*2+ct -> col
#pragma unroll
    for (int i = 0; i < 4; ++i)
#pragma unroll
        for (int j = 0; j < 4; ++j) rs[i][j] = 0.f;
#pragma unroll
    for (int i = 0; i < 16; ++i) cs[i] = 0.f;

    f32x4 acc[4][2];
    auto consume = [&](int m) {
        const unsigned short* bb = (const unsigned short*)&Bs[0][0] + ((m & 3) << 10);
        const int kc = m & 7;
        bf16x8 bf[2];
#pragma unroll
        for (int ct = 0; ct < 2; ++ct) {
            int c = (ct << 4) + n16;
            int d = q ^ (c & 3);
            bf[ct] = *(const bf16x8*)(bb + (((c << 2) | d) << 3));
        }
#pragma unroll
        for (int rt = 0; rt < 4; ++rt)
#pragma unroll
            for (int ct = 0; ct < 2; ++ct)
                acc[rt][ct] = __builtin_amdgcn_mfma_f32_16x16x32_bf16(
                    a[rt][kc], bf[ct], acc[rt][ct], 0, 0, 0);
    };
    auto acczero = [&]() {
#pragma unroll
        for (int rt = 0; rt < 4; ++rt)
#pragma unroll
            for (int ct = 0; ct < 2; ++ct) acc[rt][ct] = (f32x4){0.f, 0.f, 0.f, 0.f};
    };
    auto epilogue = [&](int cc) {
        if (!strad) {
#pragma unroll
            for (int rt = 0; rt < 4; ++rt)
#pragma unroll
                for (int ct = 0; ct < 2; ++ct)
#pragma unroll
                    for (int r = 0; r < 4; ++r) {
                        float e = __builtin_amdgcn_exp2f(acc[rt][ct][r] * TWO_LOG2E);
                        rs[rt][r] += e;
                        cs[(cc << 1) + ct] += e;
                    }
        } else {
#pragma unroll
            for (int rt = 0; rt < 4; ++rt)
#pragma unroll
                for (int ct = 0; ct < 2; ++ct) {
                    int j = colRun + (cc << 5) + (ct << 4) + n16;
#pragma unroll
                    for (int r = 0; r < 4; ++r) {
                        float e = __builtin_amdgcn_exp2f(acc[rt][ct][r] * TWO_LOG2E);
                        int i = rowBase + (rt << 4) + (q << 2) + r;
                        rs[rt][r] += (j >= i) ? e : 0.f;   // diag once, row side
                        cs[(cc << 1) + ct] += (j > i) ? e : 0.f;
                    }
                }
        }
    };

    stage(0); stage(1); stage(2);

    for (int cc = 0; cc < 7; ++cc) {            // chunks 0..55: always stage+vmcnt(6)
        acczero();
#pragma unroll
        for (int kc = 0; kc < 8; ++kc) {
            int m = (cc << 3) + kc;
            stage(m + 3);
            asm volatile("s_waitcnt vmcnt(6)" ::: "memory");
            consume(m);
        }
        epilogue(cc);
    }
    // peeled tail cc=7: chunks 56..63 (stages for 59..63 then drain 6->4->2->0)
    acczero();
#pragma unroll
    for (int kc = 0; kc < 5; ++kc) {            // m=56..60: stage m+3 (59..63)
        int m = 56 + kc;
        stage(m + 3);
        asm volatile("s_waitcnt vmcnt(6)" ::: "memory");
        consume(m);
    }
    asm volatile("s_waitcnt vmcnt(4)" ::: "memory");
    consume(61);
    asm volatile("s_waitcnt vmcnt(2)" ::: "memory");
    consume(62);
    asm volatile("s_waitcnt vmcnt(0)" ::: "memory");
    consume(63);
    epilogue(7);

    // flush row sums (C/D layout: col=n16, row=q*4+r): 16 atomics
#pragma unroll
    for (int rt = 0; rt < 4; ++rt)
#pragma unroll
        for (int r = 0; r < 4; ++r) {
            float s = rs[rt][r];
            s += __shfl_xor(s, 1, 64);
            s += __shfl_xor(s, 2, 64);
            s += __shfl_xor(s, 4, 64);
            s += __shfl_xor(s, 8, 64);
            if (n16 == 0) atomicAdd(&S[rowBase + (rt << 4) + (q << 2) + r], s);
        }
    // flush col sums (reduce over quads; lane q==0 holds col n16 of group idx)
#pragma unroll
    for (int idx = 0; idx < 16; ++idx) {
        float s = cs[idx];
        s += __shfl_xor(s, 16, 64);
        s += __shfl_xor(s, 32, 64);
        if (q == 0)
            atomicAdd(&S[colRun + ((idx >> 1) << 5) + ((idx & 1) << 4) + n16], s);
    }
}

// ---------------- kernel 3: loss = mean( log(S_i - e^{sim_ii}) - sim_{i,target} ) -------
__global__ void __launch_bounds__(256) finish_kernel(
    const unsigned short* __restrict__ zn, const float* __restrict__ S,
    float* __restrict__ out)
{
    __shared__ float vals[16];
    const int tid = threadIdx.x, lane = tid & 63, wave = tid >> 6;
    const int q = lane >> 4, n16 = lane & 15;
    const int rib = (wave << 2) + q;                // 0..15 rows per block
    const int row = (blockIdx.x << 4) + rib;        // 512 blocks * 16 rows
    const int tar = (row + 4096) & 8191;

    float drr = 0.f, drt = 0.f;
#pragma unroll
    for (int i = 0; i < 4; ++i) {
        int k = (i << 6) + (n16 << 2);
        uint2 ur = *(const uint2*)(zn + (row << 8) + k);
        uint2 ut = *(const uint2*)(zn + (tar << 8) + k);
        float a0 = __uint_as_float(ur.x << 16),  a1 = __uint_as_float(ur.x & 0xFFFF0000u);
        float a2 = __uint_as_float(ur.y << 16),  a3 = __uint_as_float(ur.y & 0xFFFF0000u);
        float b0 = __uint_as_float(ut.x << 16),  b1 = __uint_as_float(ut.x & 0xFFFF0000u);
        float b2 = __uint_as_float(ut.y << 16),  b3 = __uint_as_float(ut.y & 0xFFFF0000u);
        drr += a0 * a0 + a1 * a1 + a2 * a2 + a3 * a3;
        drt += a0 * b0 + a1 * b1 + a2 * b2 + a3 * b3;
    }
#pragma unroll
    for (int m = 1; m <= 8; m <<= 1) {
        drr += __shfl_xor(drr, m, 64);
        drt += __shfl_xor(drt, m, 64);
    }
    if (n16 == 0) {
        float Sv = S[row] - __builtin_amdgcn_exp2f(drr * TWO_LOG2E);  // remove diagonal
        vals[rib] = 0.693147180559945f * __builtin_amdgcn_logf(Sv) - 2.0f * drt;
    }
    __syncthreads();
    if (tid == 0) {
        float s = 0.f;
#pragma unroll
        for (int i = 0; i < 16; ++i) s += vals[i];
        atomicAdd(out, s * (1.0f / 8192.0f));
    }
}

extern "C" void kernel_launch(void* const* d_in, const int* in_sizes, int n_in,
                              void* d_out, int out_size, void* d_ws, size_t ws_size,
                              hipStream_t stream)
{
    const float* z1 = (const float*)d_in[0];
    const float* z2 = (const float*)d_in[1];
    unsigned short* zn = (unsigned short*)d_ws;                              // 4 MB
    float* S = (float*)((char*)d_ws + 8192 * 256 * sizeof(unsigned short));  // 32 KB
    float* out = (float*)d_out;

    normalize_kernel<<<2048, 256, 0, stream>>>(z1, z2, zn, S, out);
    simexp_kernel<<<2112, 64, 0, stream>>>(zn, S);
    finish_kernel<<<512, 256, 0, stream>>>(zn, S, out);
}

// Round 19
// 114.434 us; speedup vs baseline: 1.2632x; 1.2632x over previous
//
#include <hip/hip_runtime.h>

typedef __bf16 bf16x8 __attribute__((ext_vector_type(8)));
typedef float f32x4 __attribute__((ext_vector_type(4)));

#define TWO_LOG2E 2.88539008177792681f   // 2*log2(e): exp(2x) = exp2(x*TWO_LOG2E)

#define GLOADLDS16(g, l) __builtin_amdgcn_global_load_lds(                     \
    (const __attribute__((address_space(1))) void*)(g),                        \
    (__attribute__((address_space(3))) void*)(l), 16, 0, 0)

__device__ __forceinline__ unsigned f2bf(float f) {
    unsigned u = __float_as_uint(f);
    return (u + 0x7FFFu + ((u >> 16) & 1u)) >> 16;   // RNE
}

// ---------------- kernel 1: row-normalize z=[z1;z2] -> bf16 zn[8192][256] ---------------
// Blocks 0..31 also zero S[8192]; block 32 zeroes out[0]. (Proven form.)
__global__ void __launch_bounds__(256) normalize_kernel(
    const float* __restrict__ z1, const float* __restrict__ z2,
    unsigned short* __restrict__ zn, float* __restrict__ S, float* __restrict__ out)
{
    if (blockIdx.x < 32) S[(blockIdx.x << 8) + threadIdx.x] = 0.f;
    if (blockIdx.x == 32 && threadIdx.x == 0) out[0] = 0.f;

    const int wave = threadIdx.x >> 6, lane = threadIdx.x & 63;
    const int row = (blockIdx.x << 2) + wave;               // 2048 blocks * 4 rows
    const float* src = (row < 4096) ? (z1 + row * 256) : (z2 + (row - 4096) * 256);
    float4 v = ((const float4*)src)[lane];                  // 64 lanes * 4 = 256
    float ss = v.x * v.x + v.y * v.y + v.z * v.z + v.w * v.w;
#pragma unroll
    for (int m = 32; m > 0; m >>= 1) ss += __shfl_xor(ss, m, 64);
    float sc = 1.0f / fmaxf(sqrtf(ss), 1e-8f);
    uint2 w;
    w.x = f2bf(v.x * sc) | (f2bf(v.y * sc) << 16);
    w.y = f2bf(v.z * sc) | (f2bf(v.w * sc) << 16);
    *(uint2*)(zn + row * 256 + (lane << 2)) = w;
}

// ---------------- kernel 2: wave-autonomous sim-exp, 4096 jobs for 16 blocks/CU ---------
// R15's proven pipeline (42.9us at 2048 jobs), job size halved to raise occupancy:
// 4096 jobs = 128 row-strips(64) x 32 col-runs(256) -> 16 one-wave blocks/CU
// (LDS 8KB x 16 = 128KB, VGPR ~108 -> 4 waves/SIMD). A = 64 rows x K=256 in regs.
// B streams through a wave-private ring of FOUR 2KB LDS buffers via global_load_lds;
// steady-state `s_waitcnt vmcnt(6)` (3 stages in flight) orders DMA->ds_read (the
// compiler does NOT model this dependency — R9's NaN); peeled tail drains 6->4->2->0.
// Row sums in registers; ONE 16-atomic flush per job. NO col sums / triangular (R18:
// scattered cross-XCD atomics cost 2x). Diagonal removed in kernel 3. No __syncthreads.
__global__ void __launch_bounds__(64, 2) simexp_kernel(
    const unsigned short* __restrict__ zn, float* __restrict__ S)
{
    __shared__ __align__(16) unsigned short Bs[4][1024];    // 4 x 2 KB ring, wave-private

    const int lane = threadIdx.x;
    const int q = lane >> 4, n16 = lane & 15;
    const int job = blockIdx.x;                 // 0..4095
    const int rowBase = (job >> 5) << 6;        // strip * 64
    const int colRun  = (job & 31) << 8;        // run * 256

    // A: 64 rows x K=256 in registers (frag: row=n16, k=q*8 within 32-elem step)
    bf16x8 a[4][8];
#pragma unroll
    for (int rt = 0; rt < 4; ++rt)
#pragma unroll
        for (int ks = 0; ks < 8; ++ks)
            a[rt][ks] = *(const bf16x8*)(zn + ((rowBase + (rt << 4) + n16) << 8)
                                            + (ks << 5) + (q << 3));

    // stage chunk m (col-chunk m>>3 of 32 cols, k-chunk m&7 of 32 k): 2KB, 2 loads
    auto stage = [&](int m) {
        const int colBase = colRun + ((m >> 3) << 5);
        const int koff = (m & 7) << 5;          // elems
        unsigned short* base = (unsigned short*)&Bs[0][0] + ((m & 3) << 10);
#pragma unroll
        for (int p = 0; p < 2; ++p) {
            int s = (p << 6) + lane;            // 16B slot 0..127
            int c = s >> 2, d = s & 3;
            int k8 = d ^ (c & 3);               // XOR swizzle (b128-read friendly)
            GLOADLDS16(zn + ((colBase + c) << 8) + koff + (k8 << 3), base + (s << 3));
        }
    };

    float rs[4][4];
#pragma unroll
    for (int i = 0; i < 4; ++i)
#pragma unroll
        for (int j = 0; j < 4; ++j) rs[i][j] = 0.f;

    f32x4 acc[4][2];
    auto consume = [&](int m) {
        const unsigned short* bb = (const unsigned short*)&Bs[0][0] + ((m & 3) << 10);
        const int kc = m & 7;
        bf16x8 bf[2];
#pragma unroll
        for (int ct = 0; ct < 2; ++ct) {
            int c = (ct << 4) + n16;
            int d = q ^ (c & 3);
            bf[ct] = *(const bf16x8*)(bb + (((c << 2) | d) << 3));
        }
#pragma unroll
        for (int rt = 0; rt < 4; ++rt)
#pragma unroll
            for (int ct = 0; ct < 2; ++ct)
                acc[rt][ct] = __builtin_amdgcn_mfma_f32_16x16x32_bf16(
                    a[rt][kc], bf[ct], acc[rt][ct], 0, 0, 0);
    };
    auto acczero = [&]() {
#pragma unroll
        for (int rt = 0; rt < 4; ++rt)
#pragma unroll
            for (int ct = 0; ct < 2; ++ct) acc[rt][ct] = (f32x4){0.f, 0.f, 0.f, 0.f};
    };
    auto epilogue = [&]() {
#pragma unroll
        for (int rt = 0; rt < 4; ++rt)
#pragma unroll
            for (int ct = 0; ct < 2; ++ct)
#pragma unroll
                for (int r = 0; r < 4; ++r)
                    rs[rt][r] += __builtin_amdgcn_exp2f(acc[rt][ct][r] * TWO_LOG2E);
    };

    stage(0); stage(1); stage(2);

    for (int cc = 0; cc < 7; ++cc) {            // chunks 0..55: always stage+vmcnt(6)
        acczero();
#pragma unroll
        for (int kc = 0; kc < 8; ++kc) {
            int m = (cc << 3) + kc;
            stage(m + 3);
            asm volatile("s_waitcnt vmcnt(6)" ::: "memory");
            consume(m);
        }
        epilogue();
    }
    // peeled tail cc=7: chunks 56..63 (stages for 59..63 then drain 6->4->2->0)
    acczero();
#pragma unroll
    for (int kc = 0; kc < 5; ++kc) {            // m=56..60: stage m+3 (59..63)
        int m = 56 + kc;
        stage(m + 3);
        asm volatile("s_waitcnt vmcnt(6)" ::: "memory");
        consume(m);
    }
    asm volatile("s_waitcnt vmcnt(4)" ::: "memory");
    consume(61);
    asm volatile("s_waitcnt vmcnt(2)" ::: "memory");
    consume(62);
    asm volatile("s_waitcnt vmcnt(0)" ::: "memory");
    consume(63);
    epilogue();

    // flush once per job (C/D layout: col=n16, row=q*4+r): 16 row atomics
#pragma unroll
    for (int rt = 0; rt < 4; ++rt)
#pragma unroll
        for (int r = 0; r < 4; ++r) {
            float s = rs[rt][r];
            s += __shfl_xor(s, 1, 64);
            s += __shfl_xor(s, 2, 64);
            s += __shfl_xor(s, 4, 64);
            s += __shfl_xor(s, 8, 64);
            if (n16 == 0) atomicAdd(&S[rowBase + (rt << 4) + (q << 2) + r], s);
        }
}

// ---------------- kernel 3: loss = mean( log(S_i - e^{sim_ii}) - sim_{i,target} ) -------
__global__ void __launch_bounds__(256) finish_kernel(
    const unsigned short* __restrict__ zn, const float* __restrict__ S,
    float* __restrict__ out)
{
    __shared__ float vals[16];
    const int tid = threadIdx.x, lane = tid & 63, wave = tid >> 6;
    const int q = lane >> 4, n16 = lane & 15;
    const int rib = (wave << 2) + q;                // 0..15 rows per block
    const int row = (blockIdx.x << 4) + rib;        // 512 blocks * 16 rows
    const int tar = (row + 4096) & 8191;

    float drr = 0.f, drt = 0.f;
#pragma unroll
    for (int i = 0; i < 4; ++i) {
        int k = (i << 6) + (n16 << 2);
        uint2 ur = *(const uint2*)(zn + (row << 8) + k);
        uint2 ut = *(const uint2*)(zn + (tar << 8) + k);
        float a0 = __uint_as_float(ur.x << 16),  a1 = __uint_as_float(ur.x & 0xFFFF0000u);
        float a2 = __uint_as_float(ur.y << 16),  a3 = __uint_as_float(ur.y & 0xFFFF0000u);
        float b0 = __uint_as_float(ut.x << 16),  b1 = __uint_as_float(ut.x & 0xFFFF0000u);
        float b2 = __uint_as_float(ut.y << 16),  b3 = __uint_as_float(ut.y & 0xFFFF0000u);
        drr += a0 * a0 + a1 * a1 + a2 * a2 + a3 * a3;
        drt += a0 * b0 + a1 * b1 + a2 * b2 + a3 * b3;
    }
#pragma unroll
    for (int m = 1; m <= 8; m <<= 1) {
        drr += __shfl_xor(drr, m, 64);
        drt += __shfl_xor(drt, m, 64);
    }
    if (n16 == 0) {
        float Sv = S[row] - __builtin_amdgcn_exp2f(drr * TWO_LOG2E);  // remove diagonal
        vals[rib] = 0.693147180559945f * __builtin_amdgcn_logf(Sv) - 2.0f * drt;
    }
    __syncthreads();
    if (tid == 0) {
        float s = 0.f;
#pragma unroll
        for (int i = 0; i < 16; ++i) s += vals[i];
        atomicAdd(out, s * (1.0f / 8192.0f));
    }
}

extern "C" void kernel_launch(void* const* d_in, const int* in_sizes, int n_in,
                              void* d_out, int out_size, void* d_ws, size_t ws_size,
                              hipStream_t stream)
{
    const float* z1 = (const float*)d_in[0];
    const float* z2 = (const float*)d_in[1];
    unsigned short* zn = (unsigned short*)d_ws;                              // 4 MB
    float* S = (float*)((char*)d_ws + 8192 * 256 * sizeof(unsigned short));  // 32 KB
    float* out = (float*)d_out;

    normalize_kernel<<<2048, 256, 0, stream>>>(z1, z2, zn, S, out);
    simexp_kernel<<<4096, 64, 0, stream>>>(zn, S);
    finish_kernel<<<512, 256, 0, stream>>>(zn, S, out);
}